// Round 1
// 163.480 us; speedup vs baseline: 1.2530x; 1.2530x over previous
//
#include <hip/hip_runtime.h>

typedef unsigned short u16;
typedef unsigned int   u32;
typedef float f32x4  __attribute__((ext_vector_type(4)));
typedef short bf16x8 __attribute__((ext_vector_type(8)));
typedef short s16x4  __attribute__((ext_vector_type(4)));

__device__ __forceinline__ u16 f2b_rne(float x) {
    u32 u = __float_as_uint(x);
    return (u16)((u + 0x7fffu + ((u >> 16) & 1u)) >> 16);
}
__device__ __forceinline__ float b2f(u16 u) { return __uint_as_float((u32)u << 16); }
__device__ __forceinline__ void split1(float x, u16& h, u16& l) {
    h = f2b_rne(x);
    l = f2b_rne(x - b2f(h));
}
__device__ __forceinline__ void mk_frag(f32x4 a, f32x4 b, bf16x8& hi, bf16x8& lo) {
#pragma unroll
    for (int j = 0; j < 4; ++j) { u16 h, l; split1(a[j], h, l); hi[j] = (short)h; lo[j] = (short)l; }
#pragma unroll
    for (int j = 0; j < 4; ++j) { u16 h, l; split1(b[j], h, l); hi[4+j] = (short)h; lo[4+j] = (short)l; }
}

// ---------------------------------------------------------------------------
// kemb_all: fused embedding GEMM for BOTH cand (blocks 64..575) and rated
// (blocks 0..62; block 63 = Wm1b convert). Per block: 16 rows x 64 cols,
// K=1000, split-bf16 3-plane MFMA (identical numerics to rounds 5-9).
//
// Structure (new): 1024 threads = 16 waves. Phase S stages the 16x1000 X
// tile ONCE into LDS as pre-split hi/lo bf16 planes (pitch 1008 u16:
// row byte-stride 2016 -> (l15,q) ds_read_b128 pattern lands 8 lanes per
// 4-bank group = the wave64 b128 floor, conflict-free). Compute waves:
// col-tile = wv&3, K-quarter = wv>>2 -> 32 waves/CU (was 8). Partials
// reduced through LDS overlay (same pattern as k3v10 P2b). Kills the 4x
// redundant X conversion + 4x redundant X loads of the old kernel; We is
// still converted in-register but only once per block, spread over 16
// waves. Rated blocks additionally emit er_th (bf16, transposed) and ar
// (wave-0 MFMA vs Wa1[:,64:]) exactly as the old kemb_rated did.
// LDS: planes 2*16*1008*2 = 64,512 B; partials (16 KB) + smt (4.25 KB)
// overlay the plane region after the compute barrier. 2 blocks/CU.
// ---------------------------------------------------------------------------
__global__ __launch_bounds__(1024, 8) void kemb_all(
    const float* __restrict__ cand, const float* __restrict__ rated,
    const float* __restrict__ We, const float* __restrict__ be,
    const float* __restrict__ Wa1, const float* __restrict__ Wm1,
    float* __restrict__ ec, u16* __restrict__ er_th, float* __restrict__ ar,
    u16* __restrict__ Wm1b)
{
    const int blk = blockIdx.x;
    if (blk == 63) {                    // Wm1 (64x128) -> bf16 plane in ws
        for (int idx = threadIdx.x; idx < 8192; idx += 1024)
            Wm1b[idx] = f2b_rne(Wm1[idx]);
        return;
    }
    const bool is_rated = (blk < 64);
    const int  i0    = is_rated ? blk * 16 : (blk - 64) * 16;
    const int  Mrows = is_rated ? 1000 : 8192;
    const float* X   = is_rated ? rated : cand;

    __shared__ u16 S16[2 * 16 * 1008];  // XH plane, then XL plane
    float* Sf = (float*)S16;
    u16* XH = S16;
    u16* XL = S16 + 16 * 1008;

    const int t    = threadIdx.x;
    const int wv   = t >> 6;
    const int lane = t & 63;

    // ---- Phase S: wave wv stages row wv (coalesced f32x4 loads, split once)
    {
        const int r    = wv;
        const int arow = min(i0 + r, Mrows - 1);
        const float* xr = X + (size_t)arow * 1000;
#pragma unroll
        for (int j = 0; j < 4; ++j) {
            const int k4 = lane + j * 64;       // f32x4 index 0..249
            if (k4 < 250) {
                f32x4 v = *(const f32x4*)(xr + k4 * 4);
                s16x4 h4, l4;
#pragma unroll
                for (int jj = 0; jj < 4; ++jj) {
                    u16 hh, ll; split1(v[jj], hh, ll);
                    h4[jj] = (short)hh; l4[jj] = (short)ll;
                }
                *(s16x4*)(XH + r * 1008 + k4 * 4) = h4;
                *(s16x4*)(XL + r * 1008 + k4 * 4) = l4;
            }
        }
    }
    __syncthreads();

    // ---- Phase C: wave (ct = wv&3, h = wv>>2): 16-col tile x 250-K quarter
    const int l15 = lane & 15, q = lane >> 4;
    const int ct = wv & 3, h = wv >> 2;
    f32x4 acc = {0.f, 0.f, 0.f, 0.f};
    {
        const u16* ahp = XH + l15 * 1008;
        const u16* alp = XL + l15 * 1008;
        const float* wr = We + (size_t)(ct * 16 + l15) * 1000;

        const int kc0 = h * 256;
        const int kc1 = (h == 3) ? 992 : kc0 + 256;
        for (int kc = kc0; kc < kc1; kc += 32) {
            bf16x8 ah = *(const bf16x8*)(ahp + kc + q * 8);
            bf16x8 al = *(const bf16x8*)(alp + kc + q * 8);
            bf16x8 bh, bl;
            mk_frag(*(const f32x4*)(wr + kc + q * 8), *(const f32x4*)(wr + kc + q * 8 + 4), bh, bl);
            acc = __builtin_amdgcn_mfma_f32_16x16x32_bf16(ah, bh, acc, 0, 0, 0);
            acc = __builtin_amdgcn_mfma_f32_16x16x32_bf16(ah, bl, acc, 0, 0, 0);
            acc = __builtin_amdgcn_mfma_f32_16x16x32_bf16(al, bh, acc, 0, 0, 0);
        }
        if (h == 3) {                   // K tail 992..999 (q==0 live)
            bf16x8 ah = {0,0,0,0,0,0,0,0}, al = {0,0,0,0,0,0,0,0};
            bf16x8 bh = {0,0,0,0,0,0,0,0}, bl = {0,0,0,0,0,0,0,0};
            if (q == 0) {
                ah = *(const bf16x8*)(ahp + 992);
                al = *(const bf16x8*)(alp + 992);
                mk_frag(*(const f32x4*)(wr + 992), *(const f32x4*)(wr + 996), bh, bl);
            }
            acc = __builtin_amdgcn_mfma_f32_16x16x32_bf16(ah, bh, acc, 0, 0, 0);
            acc = __builtin_amdgcn_mfma_f32_16x16x32_bf16(ah, bl, acc, 0, 0, 0);
            acc = __builtin_amdgcn_mfma_f32_16x16x32_bf16(al, bh, acc, 0, 0, 0);
        }
    }
    __syncthreads();                    // all plane reads done -> overlay
    // partials: P[h][m][col]
#pragma unroll
    for (int r = 0; r < 4; ++r)
        Sf[h * 1024 + (q * 4 + r) * 64 + ct * 16 + l15] = acc[r];
    __syncthreads();

    // ---- Phase R: reduce K-quarters + bias; emit outputs
    {
        const int b = t >> 6, e = t & 63;
        float v = be[e] + Sf[b * 64 + e] + Sf[1024 + b * 64 + e]
                        + Sf[2048 + b * 64 + e] + Sf[3072 + b * 64 + e];
        if (!is_rated) {
            ec[(size_t)(i0 + b) * 64 + e] = v;
        } else {
            if (i0 + b < 1000) er_th[(size_t)e * 1000 + (i0 + b)] = f2b_rne(v);
            Sf[4096 + b * 68 + e] = v;  // smt tile (pitch 68), for ar MFMA
        }
    }

    if (is_rated) {
        __syncthreads();
        if (wv == 0) {                  // ar = er @ W1r^T (split fp32-class)
            f32x4 a2 = {0.f, 0.f, 0.f, 0.f};
#pragma unroll
            for (int kc = 0; kc < 64; kc += 32) {
                const float* ap = Sf + 4096 + l15 * 68 + kc + q * 8;
                const float* bp = Wa1 + l15 * 128 + 64 + kc + q * 8;
                bf16x8 ah, al, bh, bl;
                mk_frag(*(const f32x4*)ap, *(const f32x4*)(ap + 4), ah, al);
                mk_frag(*(const f32x4*)bp, *(const f32x4*)(bp + 4), bh, bl);
                a2 = __builtin_amdgcn_mfma_f32_16x16x32_bf16(ah, bh, a2, 0, 0, 0);
                a2 = __builtin_amdgcn_mfma_f32_16x16x32_bf16(ah, bl, a2, 0, 0, 0);
                a2 = __builtin_amdgcn_mfma_f32_16x16x32_bf16(al, bh, a2, 0, 0, 0);
            }
#pragma unroll
            for (int r = 0; r < 4; ++r) {
                int i = i0 + q * 4 + r;
                if (i < 1000) ar[(size_t)i * 16 + l15] = a2[r];
            }
        }
    }
}

// ---------------------------------------------------------------------------
// k3v10: unchanged (proven PASS). 16 rows / 1024 threads / 512 blocks ->
// 2 blocks/CU x 16 waves = 32 waves/CU. Single-bf16 P/er; scores stored u16
// bf16 in place (pitch 1032 u16 -> 2-way banks on MFMA A-reads, free).
// MLP layer 1 on MFMA with ws-preconverted Wm1b.
// LDS: S16 u16[16*1032] (33,024B; overlays as f32: PA[4][16][64] @0,
// PA2 @0 (after PA dead), H1 @f4096, H2 @f5120), ACL[256], SUMS[16],
// XB16 u16[16*136] (pad->2-way banks). Total 38.5 KB -> 2 blocks/CU.
// ---------------------------------------------------------------------------
__global__ __launch_bounds__(1024, 8) void k3v10(
    const float* __restrict__ ar, const float* __restrict__ ecC,
    const u16* __restrict__ er_th, const float* __restrict__ um,
    const float* __restrict__ Wa1, const float* __restrict__ ba1,
    const float* __restrict__ Wa2, const u16* __restrict__ Wm1b,
    const float* __restrict__ bm1,
    const float* __restrict__ Wm2, const float* __restrict__ bm2,
    const float* __restrict__ Wm3, const float* __restrict__ bm3,
    float* __restrict__ out)
{
    __shared__ u16   S16[16 * 1032];
    __shared__ float ACL[256];
    __shared__ float SUMS[16];
    __shared__ u16   XB16[16 * 136];
    float* Sf = (float*)S16;
    const int t  = threadIdx.x;
    const int b0 = blockIdx.x * 16;

    // P0: ACL[b][a] = ba1[a] + ec[b0+b] . W1c[a]
    if (t < 256) {
        const int a = t & 15, b = t >> 4;
        float acc = ba1[a];
        const float* ecr = ecC + (size_t)(b0 + b) * 64;
        const float* w = Wa1 + a * 128;
#pragma unroll 8
        for (int e = 0; e < 64; ++e) acc += ecr[e] * w[e];
        ACL[b * 16 + a] = acc;
    }
    __syncthreads();                                        // B1

    // P1: thread = item i; computes scores for all 16 b, writes u16 bf16.
    {
        const int i = t;
        if (i < 1000) {
            const f32x4* a4 = (const f32x4*)(ar + (size_t)i * 16);
            f32x4 r0 = a4[0], r1 = a4[1], r2 = a4[2], r3 = a4[3];
            float w2[16];
#pragma unroll
            for (int a = 0; a < 16; ++a) w2[a] = Wa2[a];
#pragma unroll 4
            for (int b = 0; b < 16; ++b) {
                const f32x4* ac4 = (const f32x4*)(ACL + b * 16);
                f32x4 c0 = ac4[0], c1 = ac4[1], c2 = ac4[2], c3 = ac4[3];
                float s0 = 0.f, s1 = 0.f;
                s0 += fmaxf(c0[0] + r0[0], 0.f) * w2[0];
                s1 += fmaxf(c0[1] + r0[1], 0.f) * w2[1];
                s0 += fmaxf(c0[2] + r0[2], 0.f) * w2[2];
                s1 += fmaxf(c0[3] + r0[3], 0.f) * w2[3];
                s0 += fmaxf(c1[0] + r1[0], 0.f) * w2[4];
                s1 += fmaxf(c1[1] + r1[1], 0.f) * w2[5];
                s0 += fmaxf(c1[2] + r1[2], 0.f) * w2[6];
                s1 += fmaxf(c1[3] + r1[3], 0.f) * w2[7];
                s0 += fmaxf(c2[0] + r2[0], 0.f) * w2[8];
                s1 += fmaxf(c2[1] + r2[1], 0.f) * w2[9];
                s0 += fmaxf(c2[2] + r2[2], 0.f) * w2[10];
                s1 += fmaxf(c2[3] + r2[3], 0.f) * w2[11];
                s0 += fmaxf(c3[0] + r3[0], 0.f) * w2[12];
                s1 += fmaxf(c3[1] + r3[1], 0.f) * w2[13];
                s0 += fmaxf(c3[2] + r3[2], 0.f) * w2[14];
                s1 += fmaxf(c3[3] + r3[3], 0.f) * w2[15];
                S16[b * 1032 + i] = f2b_rne(s0 + s1);
            }
        }
    }
    __syncthreads();                                        // B2

    // softmax: wave b (16 waves <-> 16 rows). In-place u16 -> u16.
    {
        const int b = t >> 6, g = t & 63;
        float sv[16], uv[16];
#pragma unroll
        for (int k = 0; k < 16; ++k) {
            int i = g + 64 * k;
            sv[k] = (i < 1000) ? b2f(S16[b * 1032 + i]) : -1e30f;
        }
        float m = -1e30f;
#pragma unroll
        for (int k = 0; k < 16; ++k) m = fmaxf(m, sv[k]);
#pragma unroll
        for (int k = 1; k < 64; k <<= 1) m = fmaxf(m, __shfl_xor(m, k));
        const float* umr = um + (size_t)(b0 + b) * 1000;
#pragma unroll
        for (int k = 0; k < 16; ++k) {
            int i = g + 64 * k;
            uv[k] = (i < 1000) ? umr[i] : 0.f;
        }
        float sum = 0.f;
#pragma unroll
        for (int k = 0; k < 16; ++k) {
            int i = g + 64 * k;
            if (i < 1000) {
                float w = __expf(sv[k] - m);
                sum += w;
                S16[b * 1032 + i] = f2b_rne(w * uv[k]);     // P plane in place
            }
        }
#pragma unroll
        for (int k = 1; k < 64; k <<= 1) sum += __shfl_xor(sum, k);
        if (g == 0) SUMS[b] = 1.0f / sum;
    }
    __syncthreads();                                        // B3

    // P2: user_emb = P @ er^T via single-bf16 MFMA. wave wv: e-tile = wv&3,
    // K-quarter = wv>>2. A rows m = l15 = the 16 real batch rows.
    {
        const int wv = t >> 6, lane = t & 63, l15 = lane & 15, q = lane >> 4;
        const int et = wv & 3, h = wv >> 2;
        const u16* php = S16 + l15 * 1032;
        const u16* bhp = er_th + (size_t)(et * 16 + l15) * 1000;
        f32x4 acc = {0.f, 0.f, 0.f, 0.f};

        const int kc0 = h * 256;
        const int kc1 = (h == 3) ? 992 : kc0 + 256;
        for (int kc = kc0; kc < kc1; kc += 32) {
            bf16x8 ah = *(const bf16x8*)(php + kc + q * 8);
            bf16x8 bh = *(const bf16x8*)(bhp + kc + q * 8);
            acc = __builtin_amdgcn_mfma_f32_16x16x32_bf16(ah, bh, acc, 0, 0, 0);
        }
        if (h == 3) {                   // K tail 992..999 (q==0 live)
            bf16x8 ah = {0,0,0,0,0,0,0,0}, bh = {0,0,0,0,0,0,0,0};
            if (q == 0) {
                ah = *(const bf16x8*)(php + 992);
                bh = *(const bf16x8*)(bhp + 992);
            }
            acc = __builtin_amdgcn_mfma_f32_16x16x32_bf16(ah, bh, acc, 0, 0, 0);
        }
        __syncthreads();                                    // B4: all P reads done
        // D[m = q*4+r][e-col = l15] -> PA[h][m][et*16+l15]
#pragma unroll
        for (int r = 0; r < 4; ++r)
            Sf[h * 1024 + (q * 4 + r) * 64 + et * 16 + l15] = acc[r];
    }
    __syncthreads();                                        // B5

    // P2b: combine K-quarters, scale, build x = [ec | user_emb] as bf16
    {
        const int b = t >> 6, e = t & 63;
        float v = (Sf[b * 64 + e] + Sf[1024 + b * 64 + e]
                 + Sf[2048 + b * 64 + e] + Sf[3072 + b * 64 + e]) * SUMS[b];
        XB16[b * 136 + 64 + e] = f2b_rne(v);
        XB16[b * 136 + e] = f2b_rne(ecC[(size_t)(b0 + b) * 64 + e]);
    }
    __syncthreads();                                        // B6

    // MLP layer 1 via MFMA: h1 = relu(x @ Wm1^T + bm1). wave wv: n-tile =
    // wv&3, K-quarter(32) = wv>>2. A = XB16 (pitch 136 -> 2-way banks).
    {
        const int wv = t >> 6, lane = t & 63, l15 = lane & 15, q = lane >> 4;
        const int nt = wv & 3, kh = wv >> 2;
        bf16x8 ah = *(const bf16x8*)(XB16 + l15 * 136 + kh * 32 + q * 8);
        bf16x8 bh = *(const bf16x8*)(Wm1b + (size_t)(nt * 16 + l15) * 128 + kh * 32 + q * 8);
        f32x4 acc = {0.f, 0.f, 0.f, 0.f};
        acc = __builtin_amdgcn_mfma_f32_16x16x32_bf16(ah, bh, acc, 0, 0, 0);
        // PA region dead (read at B6) -> PA2[kh][m][nt*16+l15]
#pragma unroll
        for (int r = 0; r < 4; ++r)
            Sf[kh * 1024 + (q * 4 + r) * 64 + nt * 16 + l15] = acc[r];
    }
    __syncthreads();                                        // B7

    // reduce + bias + relu -> H1 (f32 @ f-idx 4096)
    {
        const int b = t >> 6, o = t & 63;
        float a = bm1[o] + Sf[b * 64 + o] + Sf[1024 + b * 64 + o]
                + Sf[2048 + b * 64 + o] + Sf[3072 + b * 64 + o];
        Sf[4096 + b * 64 + o] = fmaxf(a, 0.f);
    }
    __syncthreads();                                        // B8

    // MLP layer 2 (64->32): wave b, lane j<32
    {
        const int b = t >> 6, j = t & 63;
        if (j < 32) {
            float a = bm2[j];
            const float* wr = Wm2 + j * 64;
            const float* x = Sf + 4096 + b * 64;
#pragma unroll 8
            for (int k = 0; k < 64; ++k) a += x[k] * wr[k];
            Sf[5120 + b * 32 + j] = fmaxf(a, 0.f);
        }
    }
    __syncthreads();                                        // B9

    // MLP layer 3 (32->1): wave b reduce
    {
        const int b = t >> 6, j = t & 63;
        float p = (j < 32) ? Sf[5120 + b * 32 + j] * Wm3[j] : 0.f;
#pragma unroll
        for (int kk = 1; kk < 64; kk <<= 1) p += __shfl_xor(p, kk);
        if (j == 0) out[b0 + b] = p + bm3[0];
    }
}

extern "C" void kernel_launch(void* const* d_in, const int* in_sizes, int n_in,
                              void* d_out, int out_size, void* d_ws, size_t ws_size,
                              hipStream_t stream) {
    const float* cand  = (const float*)d_in[0];   // (8192,1000) fp32
    const float* rated = (const float*)d_in[1];   // (1000,1000)
    const float* um    = (const float*)d_in[2];   // (8192,1000)
    const float* We    = (const float*)d_in[3];   // (64,1000)
    const float* be    = (const float*)d_in[4];   // (64,)
    const float* Wa1   = (const float*)d_in[5];   // (16,128)
    const float* ba1   = (const float*)d_in[6];   // (16,)
    const float* Wa2   = (const float*)d_in[7];   // (1,16)
    // d_in[8] = ba2: softmax-invariant (exact), skipped
    const float* Wm1   = (const float*)d_in[9];   // (64,128)
    const float* bm1   = (const float*)d_in[10];  // (64,)
    const float* Wm2   = (const float*)d_in[11];  // (32,64)
    const float* bm2   = (const float*)d_in[12];  // (32,)
    const float* Wm3   = (const float*)d_in[13];  // (1,32)
    const float* bm3   = (const float*)d_in[14];  // (1,)

    // ws: ar 64,000 + ec 2,097,152 + er_th 128,000 + Wm1b 16,384
    //   = 2,305,536 B <= 2,417,152 B (ceiling proven in-use since round 5).
    float* arw   = (float*)d_ws;                  // 16000 f
    float* ec    = arw + 16000;                   // 524288 f
    u16*   er_th = (u16*)(ec + 524288);           // 64000 u16
    u16*   wm1b  = er_th + 64000;                 // 8192 u16
    float* out   = (float*)d_out;

    // blocks 0..62: rated GEMM (+ er_th, ar); block 63: Wm1b convert;
    // blocks 64..575: cand GEMM. Rated first so its blocks overlap the bulk.
    kemb_all<<<dim3(576), dim3(1024), 0, stream>>>(cand, rated, We, be, Wa1, Wm1,
                                                   ec, er_th, arw, wm1b);
    k3v10   <<<dim3(512), dim3(1024), 0, stream>>>(arw, ec, er_th, um,
                                                   Wa1, ba1, Wa2, wm1b, bm1,
                                                   Wm2, bm2, Wm3, bm3, out);
}